// Round 1
// 1781.816 us; speedup vs baseline: 1.3182x; 1.3182x over previous
//
#include <hip/hip_runtime.h>

#define T_ROWS 16384
#define H_DIM  4096
#define EPS    1e-5f

typedef _Float16 half8v __attribute__((ext_vector_type(8)));
typedef _Float16 half4v __attribute__((ext_vector_type(4)));
typedef float    floatx4 __attribute__((ext_vector_type(4)));

__device__ __forceinline__ void async_ld16(const void* g, void* l) {
  __builtin_amdgcn_global_load_lds(
      (const __attribute__((address_space(1))) void*)g,
      (__attribute__((address_space(3))) void*)l, 16, 0, 0);
}

// ---------------------------------------------------------------------------
// w (K x N fp32, row-major) -> wt (N x K fp16, row-major)
// ---------------------------------------------------------------------------
__global__ __launch_bounds__(256) void transpose_cast(
    const float* __restrict__ in, _Float16* __restrict__ out) {
  __shared__ float tile[32][33];
  const int tx  = threadIdx.x & 31;
  const int ty4 = (threadIdx.x >> 5) << 2;
  const int nt = blockIdx.x * 32, kt = blockIdx.y * 32;
#pragma unroll
  for (int i = 0; i < 4; ++i)
    tile[ty4 + i][tx] = in[(size_t)(kt + ty4 + i) * H_DIM + nt + tx];
  __syncthreads();
#pragma unroll
  for (int i = 0; i < 4; ++i)
    out[(size_t)(nt + ty4 + i) * H_DIM + kt + tx] = (_Float16)tile[tx][ty4 + i];
}

// ---------------------------------------------------------------------------
// Row-wise RMSNorm (optionally fused relu on the input), H = 4096.
// ---------------------------------------------------------------------------
template <bool RELU, bool OUT_HALF>
__global__ __launch_bounds__(256) void rms_kernel(
    const float* __restrict__ in, const float* __restrict__ g,
    void* __restrict__ out) {
  const int tid = threadIdx.x;
  const float4* rp = (const float4*)(in + (size_t)blockIdx.x * H_DIM);
  float4 v[4];
  float ss = 0.f;
#pragma unroll
  for (int c = 0; c < 4; ++c) {
    float4 t = rp[c * 256 + tid];
    if (RELU) {
      t.x = fmaxf(t.x, 0.f); t.y = fmaxf(t.y, 0.f);
      t.z = fmaxf(t.z, 0.f); t.w = fmaxf(t.w, 0.f);
    }
    v[c] = t;
    ss += t.x * t.x + t.y * t.y + t.z * t.z + t.w * t.w;
  }
#pragma unroll
  for (int off = 32; off > 0; off >>= 1) ss += __shfl_down(ss, off);
  __shared__ float red[4];
  if ((tid & 63) == 0) red[tid >> 6] = ss;
  __syncthreads();
  ss = red[0] + red[1] + red[2] + red[3];
  const float scale = rsqrtf(ss * (1.f / H_DIM) + EPS);
  const float4* gp = (const float4*)g;
#pragma unroll
  for (int c = 0; c < 4; ++c) {
    const float4 gv = gp[c * 256 + tid];
    const float4 t = v[c];
    const float ox = t.x * scale * gv.x, oy = t.y * scale * gv.y,
                oz = t.z * scale * gv.z, ow = t.w * scale * gv.w;
    if (OUT_HALF) {
      half4v h;
      h[0] = (_Float16)ox; h[1] = (_Float16)oy;
      h[2] = (_Float16)oz; h[3] = (_Float16)ow;
      ((half4v*)out)[(size_t)blockIdx.x * 1024 + c * 256 + tid] = h;
    } else {
      float4 o; o.x = ox; o.y = oy; o.z = oz; o.w = ow;
      ((float4*)out)[(size_t)blockIdx.x * 1024 + c * 256 + tid] = o;
    }
  }
}

// ---------------------------------------------------------------------------
// C = A (MxK fp16) @ Bt^T (Bt NxK fp16) + addend (MxN fp32), out fp32.
// 256x256 tile, BK=64, 512 threads (8 waves, 2Mx4N, per-wave 128x64).
// 8-phase schedule (4 phases/K-tile, 2 K-tiles per LDS dbuf cycle):
//   T2 LDS XOR swizzle (byte[6:5] ^= row[1:0]) via pre-swizzled global src,
//   T3/T4 counted vmcnt(6) pipeline (3 half-tiles in flight, never drained),
//   T5 setprio around MFMA clusters, T1 XCD-chunked block swizzle.
// Stage order per tile: {Bh0,Bh1,Ah0,Ah1}; B frags fully read in phase 0 and
// A frags read one phase ahead so every overwrite is issued strictly after
// the victim half's reads are drained (lgkm) and barriered.
// ---------------------------------------------------------------------------
template <bool RELU_ADD>
__global__ __launch_bounds__(512, 2) void gemm8p(
    const _Float16* __restrict__ A, const _Float16* __restrict__ Bt,
    const float* __restrict__ addend, float* __restrict__ out,
    int M, int N, int K) {
  __shared__ __align__(16) char lds[131072];  // 2 bufs x (A 32K + B 32K)

  const int tid  = threadIdx.x;
  const int w    = tid >> 6;
  const int lane = tid & 63;
  const int l16  = lane & 15, quad = lane >> 4;

  // T1: bijective XCD-chunked swizzle (gridDim.x % 8 == 0)
  const int nwg = gridDim.x;
  const int sw  = ((int)blockIdx.x & 7) * (nwg >> 3) + ((int)blockIdx.x >> 3);
  const int nbx = N >> 8;
  const size_t m0 = (size_t)(sw / nbx) << 8;
  const size_t n0 = (size_t)(sw % nbx) << 8;

  const int wm = (w >> 2) << 7;  // 0 / 128
  const int wn = (w & 3)  << 6;  // 0 / 64 / 128 / 192

  // ---- swizzled ds_read bases (involution: bits[6:5] ^= row[1:0]) ----
  const int xm  = (l16 & 3) << 5;
  const int aB  = (wm + l16) * 128 + quad * 16;
  const int bB  = 32768 + (wn + l16) * 128 + quad * 16;
  const int aS0 = aB ^ xm,        aS1 = (aB + 64) ^ xm;
  const int bS0 = bB ^ xm,        bS1 = (bB + 64) ^ xm;

  // ---- staging: linear LDS dest (HW: wave base + lane*16), src pre-swizzled
  const int srow8 = (w << 3) + (lane >> 3);
  const int ksw   = ((lane & 7) << 3) ^ (((lane >> 3) & 3) << 4);
  const _Float16* aStage = A  + (m0 + srow8) * (size_t)K + ksw;
  const _Float16* bStage = Bt + (n0 + srow8) * (size_t)K + ksw;
  const int wdst = w << 10;

#define STG_A(T, h)                                                          \
  { const int d_ = ((T) & 1) << 16;                                          \
    async_ld16(aStage + (size_t)((h) * 128) * K + (size_t)(T) * 64,          \
               lds + d_ + (h) * 16384 + wdst);                               \
    async_ld16(aStage + (size_t)((h) * 128 + 64) * K + (size_t)(T) * 64,     \
               lds + d_ + (h) * 16384 + 8192 + wdst); }
#define STG_B(T, h)                                                          \
  { const int d_ = ((T) & 1) << 16;                                          \
    async_ld16(bStage + (size_t)((h) * 128) * K + (size_t)(T) * 64,          \
               lds + d_ + 32768 + (h) * 16384 + wdst);                       \
    async_ld16(bStage + (size_t)((h) * 128 + 64) * K + (size_t)(T) * 64,     \
               lds + d_ + 32768 + (h) * 16384 + 8192 + wdst); }

  // prologue: tile0 {Bh0,Bh1,Ah0,Ah1}, tile1 {Bh0,Bh1,Ah0} -> 14 loads/thread
  STG_B(0, 0); STG_B(0, 1); STG_A(0, 0); STG_A(0, 1);
  STG_B(1, 0); STG_B(1, 1); STG_A(1, 0);
  asm volatile("s_waitcnt vmcnt(6)" ::: "memory");  // tile0 landed
  __builtin_amdgcn_s_barrier();
  __builtin_amdgcn_sched_barrier(0);

  floatx4 acc[8][4] = {};
  half8v bf[4][2], afc[2][2], afn[2][2];
  const int NT = K >> 6;

#define MFMA_PAIR(I0, F)                                                      \
  _Pragma("unroll")                                                           \
  for (int j = 0; j < 4; ++j) {                                               \
    acc[I0][j] = __builtin_amdgcn_mfma_f32_16x16x32_f16(F[0][0], bf[j][0],    \
                                                        acc[I0][j], 0, 0, 0); \
    acc[I0][j] = __builtin_amdgcn_mfma_f32_16x16x32_f16(F[0][1], bf[j][1],    \
                                                        acc[I0][j], 0, 0, 0); \
    acc[I0 + 1][j] = __builtin_amdgcn_mfma_f32_16x16x32_f16(                  \
        F[1][0], bf[j][0], acc[I0 + 1][j], 0, 0, 0);                          \
    acc[I0 + 1][j] = __builtin_amdgcn_mfma_f32_16x16x32_f16(                  \
        F[1][1], bf[j][1], acc[I0 + 1][j], 0, 0, 0);                          \
  }

  for (int t = 0; t < NT; ++t) {
    const char* Ld = lds + ((t & 1) << 16);
    // ---------------- phase 0: read af(i0,1)+bf(all)+af(i2,3); stage A-h1(t+1)
    afc[0][0] = *(const half8v*)(Ld + aS0);
    afc[0][1] = *(const half8v*)(Ld + aS1);
    afc[1][0] = *(const half8v*)(Ld + aS0 + 2048);
    afc[1][1] = *(const half8v*)(Ld + aS1 + 2048);
#pragma unroll
    for (int j = 0; j < 4; ++j) {
      bf[j][0] = *(const half8v*)(Ld + bS0 + j * 2048);
      bf[j][1] = *(const half8v*)(Ld + bS1 + j * 2048);
    }
    afn[0][0] = *(const half8v*)(Ld + aS0 + 2 * 2048);
    afn[0][1] = *(const half8v*)(Ld + aS1 + 2 * 2048);
    afn[1][0] = *(const half8v*)(Ld + aS0 + 3 * 2048);
    afn[1][1] = *(const half8v*)(Ld + aS1 + 3 * 2048);
    if (t < NT - 1) STG_A(t + 1, 1);
    __builtin_amdgcn_s_barrier();
    asm volatile("s_waitcnt lgkmcnt(4)" ::: "memory");
    __builtin_amdgcn_sched_barrier(0);
    __builtin_amdgcn_s_setprio(1);
    MFMA_PAIR(0, afc)
    __builtin_amdgcn_s_setprio(0);
    __builtin_amdgcn_s_barrier();
    __builtin_amdgcn_sched_barrier(0);
    // ---------------- phase 1: read af(i4,5); stage B-h0(t+2); mfma i2,3
    afc[0][0] = *(const half8v*)(Ld + aS0 + 4 * 2048);
    afc[0][1] = *(const half8v*)(Ld + aS1 + 4 * 2048);
    afc[1][0] = *(const half8v*)(Ld + aS0 + 5 * 2048);
    afc[1][1] = *(const half8v*)(Ld + aS1 + 5 * 2048);
    if (t < NT - 2) STG_B(t + 2, 0);
    __builtin_amdgcn_s_barrier();
    asm volatile("s_waitcnt lgkmcnt(4)" ::: "memory");
    __builtin_amdgcn_sched_barrier(0);
    __builtin_amdgcn_s_setprio(1);
    MFMA_PAIR(2, afn)
    __builtin_amdgcn_s_setprio(0);
    __builtin_amdgcn_s_barrier();
    __builtin_amdgcn_sched_barrier(0);
    // ---------------- phase 2: read af(i6,7); stage B-h1(t+2); mfma i4,5
    afn[0][0] = *(const half8v*)(Ld + aS0 + 6 * 2048);
    afn[0][1] = *(const half8v*)(Ld + aS1 + 6 * 2048);
    afn[1][0] = *(const half8v*)(Ld + aS0 + 7 * 2048);
    afn[1][1] = *(const half8v*)(Ld + aS1 + 7 * 2048);
    if (t < NT - 2) STG_B(t + 2, 1);
    __builtin_amdgcn_s_barrier();
    asm volatile("s_waitcnt lgkmcnt(4)" ::: "memory");
    __builtin_amdgcn_sched_barrier(0);
    __builtin_amdgcn_s_setprio(1);
    MFMA_PAIR(4, afc)
    __builtin_amdgcn_s_setprio(0);
    // drain ALL ds_reads before phase-3's A-h0 overwrite can be issued
    asm volatile("s_waitcnt lgkmcnt(0)" ::: "memory");
    __builtin_amdgcn_s_barrier();
    __builtin_amdgcn_sched_barrier(0);
    // ---------------- phase 3: stage A-h0(t+2); mfma i6,7; tile gate
    if (t < NT - 2) STG_A(t + 2, 0);
    __builtin_amdgcn_s_barrier();
    asm volatile("s_waitcnt lgkmcnt(0)" ::: "memory");
    __builtin_amdgcn_sched_barrier(0);
    __builtin_amdgcn_s_setprio(1);
    MFMA_PAIR(6, afn)
    __builtin_amdgcn_s_setprio(0);
    if (t < NT - 2) {
      asm volatile("s_waitcnt vmcnt(6)" ::: "memory");  // next tile landed
    } else {
      asm volatile("s_waitcnt vmcnt(0)" ::: "memory");  // final drain
    }
    __builtin_amdgcn_s_barrier();
    __builtin_amdgcn_sched_barrier(0);
  }

  // epilogue: C/D layout col = lane&15, row = quad*4 + reg
  const size_t mBase = m0 + wm + (quad << 2);
  const size_t nBase = n0 + wn + l16;
#pragma unroll
  for (int i = 0; i < 8; ++i) {
#pragma unroll
    for (int r = 0; r < 4; ++r) {
      const size_t base = (mBase + i * 16 + r) * N + nBase;
#pragma unroll
      for (int j = 0; j < 4; ++j) {
        float a = addend[base + j * 16];
        if (RELU_ADD) a = fmaxf(a, 0.f);
        out[base + j * 16] = acc[i][j][r] + a;
      }
    }
  }
#undef STG_A
#undef STG_B
#undef MFMA_PAIR
}

// ---------------------------------------------------------------------------
extern "C" void kernel_launch(void* const* d_in, const int* in_sizes, int n_in,
                              void* d_out, int out_size, void* d_ws,
                              size_t ws_size, hipStream_t stream) {
  const float* x  = (const float*)d_in[0];
  const float* g0 = (const float*)d_in[1];
  const float* g1 = (const float*)d_in[2];
  const float* g2 = (const float*)d_in[3];
  const float* w0 = (const float*)d_in[4];
  const float* w1 = (const float*)d_in[5];
  float* out = (float*)d_out;

  char* ws = (char*)d_ws;
  _Float16* w0t  = (_Float16*)ws;                    // 32 MB
  _Float16* w1t  = (_Float16*)(ws + 33554432ull);    // 32 MB
  _Float16* y    = (_Float16*)(ws + 67108864ull);    // 128 MB (reused y0/y1)
  float*    res2 = (float*)   (ws + 201326592ull);   // 256 MB

  const dim3 tgrid(H_DIM / 32, H_DIM / 32);
  transpose_cast<<<tgrid, 256, 0, stream>>>(w0, w0t);
  transpose_cast<<<tgrid, 256, 0, stream>>>(w1, w1t);

  // y0 = rmsnorm(relu(x)) * g0   (fp16)
  rms_kernel<true, true><<<T_ROWS, 256, 0, stream>>>(x, g0, y);

  const dim3 ggrid((T_ROWS / 256) * (H_DIM / 256));  // 1024 blocks
  // res2 = y0 @ w0 + relu(x)
  gemm8p<true><<<ggrid, 512, 0, stream>>>(y, w0t, x, res2,
                                          T_ROWS, H_DIM, H_DIM);
  // y1 = rmsnorm(res2) * g1  (fp16)
  rms_kernel<false, true><<<T_ROWS, 256, 0, stream>>>(res2, g1, y);
  // out = y1 @ w1 + res2   (resid3 staged in d_out)
  gemm8p<false><<<ggrid, 512, 0, stream>>>(y, w1t, res2, out,
                                           T_ROWS, H_DIM, H_DIM);
  // out = rmsnorm(out) * g2, in-place (each block owns its full row)
  rms_kernel<false, false><<<T_ROWS, 256, 0, stream>>>(out, g2, out);
}